// Round 3
// baseline (346.447 us; speedup 1.0000x reference)
//
#include <hip/hip_runtime.h>
#include <stdint.h>

#define SEQ 2048
#define BATCH 4
#define EMB 512
#define MTOT (BATCH * SEQ)   // 8192 rows
#define WIN 16
#define WINDOW 33            // 2*WIN+1
#define NBLK 512

typedef uint32_t u32;
typedef unsigned short u16;
typedef __attribute__((ext_vector_type(8))) __bf16 bf16x8;
typedef __attribute__((ext_vector_type(4))) float f32x4;
typedef __attribute__((ext_vector_type(4))) u16 u16x4;
typedef __attribute__((ext_vector_type(8))) u16 u16x8;

__device__ __forceinline__ u16 f2bf(float f) {  // RNE f32->bf16
  u32 u = __builtin_bit_cast(u32, f);
  u = (u + 0x7fffu + ((u >> 16) & 1u)) >> 16;
  return (u16)u;
}
__device__ __forceinline__ float bf2f(u16 v) {
  return __builtin_bit_cast(float, (u32)v << 16);
}
__device__ __forceinline__ void gload16(void* lds, const void* g) {
  __builtin_amdgcn_global_load_lds((const __attribute__((address_space(1))) u32*)g,
                                   (__attribute__((address_space(3))) u32*)lds, 16, 0, 0);
}

// Device-scope grid barrier. Counters zeroed by hipMemsetAsync before launch.
// Co-residency guaranteed: __launch_bounds__(256,2) + 51456B LDS -> >=2 blocks/CU x 256 CU >= 512.
__device__ __forceinline__ void gridbar(u32* cnt, int id) {
  __syncthreads();
  if (threadIdx.x == 0) {
    __threadfence();  // release all prior writes device-wide
    __hip_atomic_fetch_add(cnt + id, 1u, __ATOMIC_ACQ_REL, __HIP_MEMORY_SCOPE_AGENT);
    while (__hip_atomic_load(cnt + id, __ATOMIC_ACQUIRE, __HIP_MEMORY_SCOPE_AGENT) < NBLK)
      __builtin_amdgcn_s_sleep(8);
    __threadfence();
  }
  __syncthreads();
}

__global__ void __launch_bounds__(256, 2) mega_kernel(
    const float* __restrict__ x, const float* __restrict__ Wq, const float* __restrict__ Wk,
    const float* __restrict__ Wv, const float* __restrict__ Wo,
    const float* __restrict__ bq, const float* __restrict__ bk,
    const float* __restrict__ bv, const float* __restrict__ bo,
    u16* __restrict__ xb, u16* __restrict__ WqT, u16* __restrict__ WkT,
    u16* __restrict__ Wvb, u16* __restrict__ Wob, u16* __restrict__ bvb,
    float* __restrict__ cvec, float* __restrict__ econst,
    u16* __restrict__ Atm, u16* __restrict__ Vb, float* __restrict__ e_part,
    float* __restrict__ out, u32* __restrict__ bar) {
  // LDS union: window phase needs 48K Vt + 192 eloc + 2112 w = 51456 (max). GEMMs use 16K.
  __shared__ __align__(16) char smem[51456];
  int b = blockIdx.x;
  int t = threadIdx.x;
  int wave = t >> 6, lane = t & 63;
  int fr = lane & 15, fq = lane >> 4;

  // ================= P0: weight transposes/casts + cvec + econst + bvb =================
  {
    // Wv / Wo cast: 512 floats of each per block (float2 per thread)
    {
      float2 v = *reinterpret_cast<const float2*>(Wv + (size_t)b * 512 + t * 2);
      u32 o = (u32)f2bf(v.x) | ((u32)f2bf(v.y) << 16);
      *reinterpret_cast<u32*>(Wvb + (size_t)b * 512 + t * 2) = o;
      float2 v2 = *reinterpret_cast<const float2*>(Wo + (size_t)b * 512 + t * 2);
      o = (u32)f2bf(v2.x) | ((u32)f2bf(v2.y) << 16);
      *reinterpret_cast<u32*>(Wob + (size_t)b * 512 + t * 2) = o;
    }
    // transpose-cast one 32x32 tile of Wq (b<256) or Wk (b>=256)
    {
      float (*tile)[33] = reinterpret_cast<float (*)[33]>(smem);
      bool isQ = b < 256;
      int tb = b & 255;
      const float* S = isQ ? Wq : Wk;
      u16* D = isQ ? WqT : WkT;
      int ti = tb >> 4, tj = tb & 15;
      int lr = t >> 5, lc = t & 31;
#pragma unroll
      for (int rr = 0; rr < 32; rr += 8)
        tile[rr + lr][lc] = S[(size_t)(ti * 32 + rr + lr) * EMB + tj * 32 + lc];
      __syncthreads();
      int jr = t >> 3, dc = (t & 7) * 4;
      u16x4 o;
#pragma unroll
      for (int c = 0; c < 4; ++c) o[c] = f2bf(tile[dc + c][jr]);
      *reinterpret_cast<u16x4*>(D + (size_t)(tj * 32 + jr) * EMB + ti * 32 + dc) = o;
      __syncthreads();
    }
    // cvec[b] = sum_d Wq[d][b]*bk[d] + Wk[d][b]*bq[d]
    {
      float* sh = reinterpret_cast<float*>(smem);
      float s = Wq[(size_t)t * EMB + b] * bk[t] + Wq[(size_t)(t + 256) * EMB + b] * bk[t + 256]
              + Wk[(size_t)t * EMB + b] * bq[t] + Wk[(size_t)(t + 256) * EMB + b] * bq[t + 256];
      sh[t] = s;
      __syncthreads();
      for (int st = 128; st > 0; st >>= 1) {
        if (t < st) sh[t] += sh[t + st];
        __syncthreads();
      }
      if (t == 0) cvec[b] = sh[0];
      if (b == 0) {  // econst = bq.bk
        __syncthreads();
        float s2 = bq[t] * bk[t] + bq[t + 256] * bk[t + 256];
        sh[t] = s2;
        __syncthreads();
        for (int st = 128; st > 0; st >>= 1) {
          if (t < st) sh[t] += sh[t + st];
          __syncthreads();
        }
        if (t == 0) *econst = sh[0];
      }
      if (b == 1) { bvb[t] = f2bf(bv[t]); bvb[t + 256] = f2bf(bv[t + 256]); }
    }
  }

  gridbar(bar, 0);

  // ================= P1: At = WkT @ WqT^T (64 blocks, 64x64 tiles) || x-cast (448 blocks) ==
  if (b < 64) {
    u16* At2 = (u16*)smem;            // 64x32 bf16
    u16* Bt2 = (u16*)(smem + 4096);   // 64x32 bf16
    int bx = b >> 3, by = b & 7;
    int a0 = bx * 64, b0 = by * 64;
    int wr = wave >> 1, wc = wave & 1;
    f32x4 acc[2][2] = {};
    for (int kt = 0; kt < EMB / 32; ++kt) {
      __syncthreads();
      int kb = kt * 32;
      int row = t >> 2, col = (t & 3) * 8;
      gload16(At2 + (size_t)t * 8, WkT + (size_t)(a0 + row) * EMB + kb + col);
      gload16(Bt2 + (size_t)t * 8, WqT + (size_t)(b0 + row) * EMB + kb + col);
      __syncthreads();
      bf16x8 af[2], bfv[2];
#pragma unroll
      for (int m = 0; m < 2; ++m)
        af[m] = *reinterpret_cast<const bf16x8*>(&At2[(wr * 32 + m * 16 + fr) * 32 + fq * 8]);
#pragma unroll
      for (int n = 0; n < 2; ++n)
        bfv[n] = *reinterpret_cast<const bf16x8*>(&Bt2[(wc * 32 + n * 16 + fr) * 32 + fq * 8]);
#pragma unroll
      for (int m = 0; m < 2; ++m)
#pragma unroll
        for (int n = 0; n < 2; ++n)
          acc[m][n] = __builtin_amdgcn_mfma_f32_16x16x32_bf16(af[m], bfv[n], acc[m][n], 0, 0, 0);
    }
#pragma unroll
    for (int m = 0; m < 2; ++m)
#pragma unroll
      for (int n = 0; n < 2; ++n)
#pragma unroll
        for (int r = 0; r < 4; ++r)
          Atm[(size_t)(a0 + wr * 32 + m * 16 + fq * 4 + r) * EMB + b0 + wc * 32 + n * 16 + fr] =
              f2bf(acc[m][n][r]);
  } else {
    // x cast: grid-stride over 1M float4s with 448 blocks
    int nb = b - 64;
    for (u32 idx = nb * 256 + t; idx < (u32)(MTOT * EMB / 4); idx += 448 * 256) {
      float4 v = reinterpret_cast<const float4*>(x)[idx];
      u16x4 o; o.x = f2bf(v.x); o.y = f2bf(v.y); o.z = f2bf(v.z); o.w = f2bf(v.w);
      reinterpret_cast<u16x4*>(xb)[idx] = o;
    }
  }

  gridbar(bar, 1);

  // ================= P2: E rowdot (by<4) + V GEMM (by>=4), 128x128 tiles =================
  {
    u16* At = (u16*)smem;
    u16* Bt = (u16*)(smem + 8192);
    int wg = ((b & 7) << 6) + (b >> 3);   // XCD-chunked swizzle
    int by = wg & 7, bx = wg >> 3;
    bool isE = by < 4;
    int wr = wave >> 1, wc = wave & 1;
    int m0 = bx * 128;
    int n0 = (by & 3) * 128;
    const u16* Bm = isE ? Atm : Wvb;
    f32x4 acc[4][4] = {};
    for (int kt = 0; kt < EMB / 32; ++kt) {
      __syncthreads();
      int kb = kt * 32;
#pragma unroll
      for (int it = 0; it < 2; ++it) {
        int chunk = t + it * 256;
        int row = chunk >> 2, col = (chunk & 3) * 8;
        gload16(At + (size_t)(wave * 64 + it * 256) * 8, xb + (size_t)(m0 + row) * EMB + kb + col);
        gload16(Bt + (size_t)(wave * 64 + it * 256) * 8, Bm + (size_t)(n0 + row) * EMB + kb + col);
      }
      __syncthreads();
      bf16x8 af[4], bfv[4];
#pragma unroll
      for (int m = 0; m < 4; ++m)
        af[m] = *reinterpret_cast<const bf16x8*>(&At[(wr * 64 + m * 16 + fr) * 32 + fq * 8]);
#pragma unroll
      for (int n = 0; n < 4; ++n)
        bfv[n] = *reinterpret_cast<const bf16x8*>(&Bt[(wc * 64 + n * 16 + fr) * 32 + fq * 8]);
#pragma unroll
      for (int m = 0; m < 4; ++m)
#pragma unroll
        for (int n = 0; n < 4; ++n)
          acc[m][n] = __builtin_amdgcn_mfma_f32_16x16x32_bf16(af[m], bfv[n], acc[m][n], 0, 0, 0);
    }
    if (isE) {
      float cv[4];
#pragma unroll
      for (int n = 0; n < 4; ++n) cv[n] = cvec[n0 + wc * 64 + n * 16 + fr];
#pragma unroll
      for (int m = 0; m < 4; ++m) {
#pragma unroll
        for (int r = 0; r < 4; ++r) {
          int row = m0 + wr * 64 + m * 16 + fq * 4 + r;
          float p = 0.f;
#pragma unroll
          for (int n = 0; n < 4; ++n) {
            int col = n0 + wc * 64 + n * 16 + fr;
            p += (acc[m][n][r] + cv[n]) * x[(size_t)row * EMB + col];
          }
          p += __shfl_xor(p, 1);
          p += __shfl_xor(p, 2);
          p += __shfl_xor(p, 4);
          p += __shfl_xor(p, 8);
          if (fr == 0) e_part[(size_t)(by * 2 + wc) * MTOT + row] = p;
        }
      }
    } else {
      float bvv[4];
#pragma unroll
      for (int n = 0; n < 4; ++n) bvv[n] = bv[n0 + wc * 64 + n * 16 + fr];
#pragma unroll
      for (int m = 0; m < 4; ++m)
#pragma unroll
        for (int n = 0; n < 4; ++n) {
          int col = n0 + wc * 64 + n * 16 + fr;
#pragma unroll
          for (int r = 0; r < 4; ++r) {
            int row = m0 + wr * 64 + m * 16 + fq * 4 + r;
            Vb[(size_t)row * EMB + col] = f2bf(acc[m][n][r] + bvv[n]);
          }
        }
    }
  }

  gridbar(bar, 2);

  // ================= P3: window softmax + weighted V sum -> ao (= xb buffer) =============
  {
    u16* Vt = (u16*)smem;                                    // 48 rows x 512 bf16
    float* eloc = (float*)(smem + 49152);                    // 48
    float (*w)[WINDOW] = (float (*)[WINDOW])(smem + 49344);  // 16 x 33
    int bb = b >> 7;
    int s0 = (b & 127) * 16;
#pragma unroll
    for (int i = 0; i < 12; ++i) {
      int chunk = t + i * 256;
      int row = chunk >> 6;
      int c8 = (chunk & 63) * 8;
      int n = s0 + row - WIN;
      const u16* src = (n >= 0 && n < SEQ) ? (Vb + (size_t)(bb * SEQ + n) * EMB + c8)
                                           : (bvb + c8);
      gload16(Vt + (size_t)(wave * 64 + i * 256) * 8, src);
    }
    const float scale = 0.044194173824159216f;  // 1/sqrt(512)
    float ec = *econst;
    if (t < 48) {
      int n = s0 + t - WIN;
      float raw = 0.f;
      if (n >= 0 && n < SEQ) {
        size_t idx = (size_t)bb * SEQ + n;
#pragma unroll
        for (int p = 0; p < 8; ++p) raw += e_part[(size_t)p * MTOT + idx];
      }
      eloc[t] = scale * (raw + ec);
    }
    __syncthreads();
    if (t < 16) {
      float ev[WINDOW];
      float mx = -1e30f;
#pragma unroll
      for (int j = 0; j < WINDOW; ++j) { ev[j] = eloc[t + j]; mx = fmaxf(mx, ev[j]); }
      float sum = 0.f;
#pragma unroll
      for (int j = 0; j < WINDOW; ++j) { float ex = __expf(ev[j] - mx); ev[j] = ex; sum += ex; }
      float inv = 1.f / sum;
#pragma unroll
      for (int j = 0; j < WINDOW; ++j) w[t][j] = ev[j] * inv;
    }
    __syncthreads();
    int cg = t & 63;
    int slg = t >> 6;
    int d0 = cg * 8;
    float oacc[4][8] = {};
    for (int ri = 0; ri < 36; ++ri) {
      int r = slg * 4 + ri;
      u16x8 v = *reinterpret_cast<const u16x8*>(&Vt[(size_t)r * EMB + d0]);
      float vf[8];
#pragma unroll
      for (int c = 0; c < 8; ++c) vf[c] = bf2f(v[c]);
#pragma unroll
      for (int q = 0; q < 4; ++q) {
        int j = ri - q;
        if (j >= 0 && j < WINDOW) {
          float wt = w[slg * 4 + q][j];
#pragma unroll
          for (int c = 0; c < 8; ++c) oacc[q][c] += wt * vf[c];
        }
      }
    }
#pragma unroll
    for (int q = 0; q < 4; ++q) {
      u16x8 o;
#pragma unroll
      for (int c = 0; c < 8; ++c) o[c] = f2bf(oacc[q][c]);
      *reinterpret_cast<u16x8*>(&xb[(size_t)(bb * SEQ + s0 + slg * 4 + q) * EMB + d0]) = o;
    }
  }

  gridbar(bar, 3);

  // ================= P4: out = ao @ Wo^T + bo (fp32), 64x128 tiles, 512 blocks ===========
  {
    u16* At2 = (u16*)smem;            // 64x32
    u16* Bt2 = (u16*)(smem + 4096);   // 128x32
    int wg = ((b & 7) << 6) + (b >> 3);
    int bx = wg >> 2, by = wg & 3;
    int wr = wave >> 1, wc = wave & 1;
    int m0 = bx * 64, n0 = by * 128;
    f32x4 acc[2][4] = {};
    for (int kt = 0; kt < EMB / 32; ++kt) {
      __syncthreads();
      int kb = kt * 32;
      {
        int row = t >> 2, col = (t & 3) * 8;
        gload16(At2 + (size_t)t * 8, xb + (size_t)(m0 + row) * EMB + kb + col);
      }
#pragma unroll
      for (int it = 0; it < 2; ++it) {
        int chunk = t + it * 256;
        int row = chunk >> 2, col = (chunk & 3) * 8;
        gload16(Bt2 + (size_t)(wave * 64 + it * 256) * 8, Wob + (size_t)(n0 + row) * EMB + kb + col);
      }
      __syncthreads();
      bf16x8 af[2], bfv[4];
#pragma unroll
      for (int m = 0; m < 2; ++m)
        af[m] = *reinterpret_cast<const bf16x8*>(&At2[(wr * 32 + m * 16 + fr) * 32 + fq * 8]);
#pragma unroll
      for (int n = 0; n < 4; ++n)
        bfv[n] = *reinterpret_cast<const bf16x8*>(&Bt2[(wc * 64 + n * 16 + fr) * 32 + fq * 8]);
#pragma unroll
      for (int m = 0; m < 2; ++m)
#pragma unroll
        for (int n = 0; n < 4; ++n)
          acc[m][n] = __builtin_amdgcn_mfma_f32_16x16x32_bf16(af[m], bfv[n], acc[m][n], 0, 0, 0);
    }
    float bov[4];
#pragma unroll
    for (int n = 0; n < 4; ++n) bov[n] = bo[n0 + wc * 64 + n * 16 + fr];
#pragma unroll
    for (int m = 0; m < 2; ++m)
#pragma unroll
      for (int n = 0; n < 4; ++n) {
        int col = n0 + wc * 64 + n * 16 + fr;
#pragma unroll
        for (int r = 0; r < 4; ++r) {
          int row = m0 + wr * 32 + m * 16 + fq * 4 + r;
          out[(size_t)row * EMB + col] = acc[m][n][r] + bov[n];
        }
      }
  }
}

extern "C" void kernel_launch(void* const* d_in, const int* in_sizes, int n_in,
                              void* d_out, int out_size, void* d_ws, size_t ws_size,
                              hipStream_t stream) {
  const float* x  = (const float*)d_in[0];
  const float* Wq = (const float*)d_in[1];
  const float* bq = (const float*)d_in[2];
  const float* Wk = (const float*)d_in[3];
  const float* bk = (const float*)d_in[4];
  const float* Wv = (const float*)d_in[5];
  const float* bv = (const float*)d_in[6];
  const float* Wo = (const float*)d_in[7];
  const float* bo = (const float*)d_in[8];
  float* out = (float*)d_out;

  char* ws = (char*)d_ws;
  u16* xb       = (u16*)(ws);                                    // 8 MB (reused as attn_out)
  u16* Vb       = (u16*)(ws + (8u << 20));                       // 8 MB
  u16* Atm      = (u16*)(ws + (16u << 20));                      // 512 KB
  u16* Wvb      = (u16*)(ws + (16u << 20) + (512u << 10));       // 512 KB
  u16* Wob      = (u16*)(ws + (16u << 20) + (1024u << 10));      // 512 KB
  u16* WqT      = (u16*)(ws + (16u << 20) + (1536u << 10));      // 512 KB
  u16* WkT      = (u16*)(ws + (16u << 20) + (2048u << 10));      // 512 KB
  float* e_part = (float*)(ws + (16u << 20) + (2560u << 10));    // 256 KB
  float* cvec   = (float*)(ws + (16u << 20) + (2816u << 10));    // 2 KB
  u16* bvb      = (u16*)(ws + (16u << 20) + (2818u << 10));      // 1 KB
  float* econst = (float*)(ws + (16u << 20) + (2819u << 10));    // 4 B
  u32* bar      = (u32*)(ws + (16u << 20) + (2820u << 10));      // 64 B barrier cells

  hipMemsetAsync(bar, 0, 64, stream);
  mega_kernel<<<NBLK, 256, 0, stream>>>(x, Wq, Wk, Wv, Wo, bq, bk, bv, bo,
                                        xb, WqT, WkT, Wvb, Wob, bvb, cvec, econst,
                                        Atm, Vb, e_part, out, bar);
}

// Round 4
// 92.072 us; speedup vs baseline: 3.7628x; 3.7628x over previous
//
#include <hip/hip_runtime.h>
#include <stdint.h>

#define SEQ 2048
#define BATCH 4
#define EMB 512
#define MTOT (BATCH * SEQ)   // 8192 rows
#define WIN 16
#define WINDOW 33            // 2*WIN+1

typedef uint32_t u32;
typedef unsigned short u16;
typedef __attribute__((ext_vector_type(8))) __bf16 bf16x8;
typedef __attribute__((ext_vector_type(4))) float f32x4;
typedef __attribute__((ext_vector_type(4))) u16 u16x4;
typedef __attribute__((ext_vector_type(8))) u16 u16x8;

__device__ __forceinline__ u16 f2bf(float f) {  // RNE f32->bf16
  u32 u = __builtin_bit_cast(u32, f);
  u = (u + 0x7fffu + ((u >> 16) & 1u)) >> 16;
  return (u16)u;
}
__device__ __forceinline__ float bf2f(u16 v) {
  return __builtin_bit_cast(float, (u32)v << 16);
}
__device__ __forceinline__ void gload16(void* lds, const void* g) {
  __builtin_amdgcn_global_load_lds((const __attribute__((address_space(1))) u32*)g,
                                   (__attribute__((address_space(3))) u32*)lds, 16, 0, 0);
}

// ============ launch 1: Wv/Wo casts || fp32 atmat || cvec || econst+bvb ============
// blocks [0,256): Wv cast | [256,512): Wo cast | [512,768): atmat 32x32 tiles |
// [768,776): cvec | 776: econst + bvb
__global__ void __launch_bounds__(256) prep1(
    const float* __restrict__ Wq, const float* __restrict__ Wk,
    const float* __restrict__ Wv, const float* __restrict__ Wo,
    const float* __restrict__ bq, const float* __restrict__ bk, const float* __restrict__ bv,
    u16* __restrict__ Wvb, u16* __restrict__ Wob, u16* __restrict__ Atm,
    u16* __restrict__ bvb, float* __restrict__ cvec, float* __restrict__ econst) {
  __shared__ float sm[2][32][36];   // atmat tiles (float4-aligned, conflict-free)
  int b = blockIdx.x, t = threadIdx.x;
  if (b < 512) {                          // ---- Wv / Wo cast (float4/thread)
    const float* S = (b < 256) ? Wv : Wo;
    u16* D = (b < 256) ? Wvb : Wob;
    int i = ((b & 255) * 256 + t) * 4;
    float4 v = *reinterpret_cast<const float4*>(S + i);
    u16x4 o; o.x = f2bf(v.x); o.y = f2bf(v.y); o.z = f2bf(v.z); o.w = f2bf(v.w);
    *reinterpret_cast<u16x4*>(D + i) = o;
  } else if (b < 768) {                   // ---- At[n][k] = sum_d Wk[d][n]*Wq[d][k]
    int bid = b - 512;
    int k0 = (bid & 15) * 32, n0 = (bid >> 4) * 32;
    int lr = t >> 5, lc = t & 31;         // lr: 8 row-groups of 4, lc: col
    float acc[4] = {0.f, 0.f, 0.f, 0.f};
    for (int d0 = 0; d0 < EMB; d0 += 32) {
      __syncthreads();
#pragma unroll
      for (int rr = 0; rr < 32; rr += 8) {
        sm[0][rr + lr][lc] = Wk[(size_t)(d0 + rr + lr) * EMB + n0 + lc];
        sm[1][rr + lr][lc] = Wq[(size_t)(d0 + rr + lr) * EMB + k0 + lc];
      }
      __syncthreads();
#pragma unroll 8
      for (int d = 0; d < 32; ++d) {
        float q = sm[1][d][lc];                                   // broadcast per lane
        float4 kv = *reinterpret_cast<const float4*>(&sm[0][d][lr * 4]);  // b128 broadcast
        acc[0] += kv.x * q; acc[1] += kv.y * q; acc[2] += kv.z * q; acc[3] += kv.w * q;
      }
    }
#pragma unroll
    for (int i = 0; i < 4; ++i)
      Atm[(size_t)(n0 + lr * 4 + i) * EMB + k0 + lc] = f2bf(acc[i]);
  } else if (b < 776) {                   // ---- cvec[i] = sum_d Wq[d][i]*bk[d]+Wk[d][i]*bq[d]
    float* sh = &sm[0][0][0];
    int cb = b - 768;
    int ii = t >> 2, di = t & 3;
    int i = cb * 64 + ii;
    float s = 0.f;
    for (int d = di * 128; d < di * 128 + 128; ++d)
      s += Wq[(size_t)d * EMB + i] * bk[d] + Wk[(size_t)d * EMB + i] * bq[d];
    sh[t] = s;
    __syncthreads();
    if (di == 0) cvec[i] = sh[t] + sh[t + 1] + sh[t + 2] + sh[t + 3];
  } else {                                // ---- econst = bq.bk ; bvb cast
    float* sh = &sm[0][0][0];
    bvb[t] = f2bf(bv[t]);
    bvb[t + 256] = f2bf(bv[t + 256]);
    float s = bq[t] * bk[t] + bq[t + 256] * bk[t + 256];
    sh[t] = s;
    __syncthreads();
    for (int st = 128; st > 0; st >>= 1) {
      if (t < st) sh[t] += sh[t + st];
      __syncthreads();
    }
    if (t == 0) *econst = sh[0];
  }
}

// ============ launch 2: E rowdot (by<4) + V GEMM (by>=4); A self-staged from fp32 x ======
__global__ void __launch_bounds__(256) gemm_ev2(
    const float* __restrict__ x, const u16* __restrict__ Atm, const u16* __restrict__ Wvb,
    const float* __restrict__ bv, const float* __restrict__ cvec,
    float* __restrict__ e_part, u16* __restrict__ Vb) {
  __shared__ u16 AtL[128 * 32];
  __shared__ u16 BtL[128 * 32];
  int b = blockIdx.x;                    // 512 blocks
  int wg = ((b & 7) << 6) + (b >> 3);    // XCD-chunked swizzle (bijective: 512 = 8*64)
  int by = wg & 7, bx = wg >> 3;
  bool isE = by < 4;
  int t = threadIdx.x;
  int wave = t >> 6, lane = t & 63;
  int wr = wave >> 1, wc = wave & 1;
  int fr = lane & 15, fq = lane >> 4;
  int m0 = bx * 128;
  int n0 = (by & 3) * 128;
  const u16* Bm = isE ? Atm : Wvb;
  f32x4 acc[4][4] = {};
  for (int kt = 0; kt < EMB / 32; ++kt) {
    __syncthreads();
    int kb = kt * 32;
    // B tile: bf16 source, async DMA to LDS
#pragma unroll
    for (int it = 0; it < 2; ++it) {
      int chunk = t + it * 256;
      int row = chunk >> 2, col = (chunk & 3) * 8;
      gload16(BtL + (size_t)(wave * 64 + it * 256) * 8, Bm + (size_t)(n0 + row) * EMB + kb + col);
    }
    // A tile: fp32 x -> cast -> LDS (reg-staged)
#pragma unroll
    for (int p = 0; p < 4; ++p) {
      int row = p * 32 + (t >> 3), col = (t & 7) * 4;
      float4 v = *reinterpret_cast<const float4*>(x + (size_t)(m0 + row) * EMB + kb + col);
      u16x4 o; o.x = f2bf(v.x); o.y = f2bf(v.y); o.z = f2bf(v.z); o.w = f2bf(v.w);
      *reinterpret_cast<u16x4*>(AtL + row * 32 + col) = o;
    }
    __syncthreads();
    bf16x8 af[4], bfv[4];
#pragma unroll
    for (int m = 0; m < 4; ++m)
      af[m] = *reinterpret_cast<const bf16x8*>(&AtL[(wr * 64 + m * 16 + fr) * 32 + fq * 8]);
#pragma unroll
    for (int n = 0; n < 4; ++n)
      bfv[n] = *reinterpret_cast<const bf16x8*>(&BtL[(wc * 64 + n * 16 + fr) * 32 + fq * 8]);
#pragma unroll
    for (int m = 0; m < 4; ++m)
#pragma unroll
      for (int n = 0; n < 4; ++n)
        acc[m][n] = __builtin_amdgcn_mfma_f32_16x16x32_bf16(af[m], bfv[n], acc[m][n], 0, 0, 0);
  }
  if (isE) {
    float cv[4];
#pragma unroll
    for (int n = 0; n < 4; ++n) cv[n] = cvec[n0 + wc * 64 + n * 16 + fr];
#pragma unroll
    for (int m = 0; m < 4; ++m) {
#pragma unroll
      for (int r = 0; r < 4; ++r) {
        int row = m0 + wr * 64 + m * 16 + fq * 4 + r;
        float p = 0.f;
#pragma unroll
        for (int n = 0; n < 4; ++n) {
          int col = n0 + wc * 64 + n * 16 + fr;
          p += (acc[m][n][r] + cv[n]) * x[(size_t)row * EMB + col];
        }
        p += __shfl_xor(p, 1);
        p += __shfl_xor(p, 2);
        p += __shfl_xor(p, 4);
        p += __shfl_xor(p, 8);
        if (fr == 0) e_part[(size_t)(by * 2 + wc) * MTOT + row] = p;
      }
    }
  } else {
    float bvv[4];
#pragma unroll
    for (int n = 0; n < 4; ++n) bvv[n] = bv[n0 + wc * 64 + n * 16 + fr];
#pragma unroll
    for (int m = 0; m < 4; ++m)
#pragma unroll
      for (int n = 0; n < 4; ++n) {
        int col = n0 + wc * 64 + n * 16 + fr;
#pragma unroll
        for (int r = 0; r < 4; ++r) {
          int row = m0 + wr * 64 + m * 16 + fq * 4 + r;
          Vb[(size_t)row * EMB + col] = f2bf(acc[m][n][r] + bvv[n]);
        }
      }
  }
}

// ============ launch 3: window softmax + PV (LDS) + fused O-projection ============
__global__ void __launch_bounds__(256) winout(
    const u16* __restrict__ Vb, const float* __restrict__ e_part,
    const float* __restrict__ econst_p, const u16* __restrict__ bvb,
    const u16* __restrict__ Wob, const float* __restrict__ bo,
    float* __restrict__ out) {
  __shared__ __align__(16) char smem[51456];
  u16* Vt = (u16*)smem;                                    // 48 x 512 bf16 = 49152 B
  float* eloc = (float*)(smem + 49152);                    // 48 floats
  float (*w)[WINDOW] = (float (*)[WINDOW])(smem + 49344);  // 16 x 33 floats
  int b = blockIdx.x;                    // 512 blocks
  int swz = ((b & 7) << 6) + (b >> 3);   // XCD-chunked (neighbor s0 share V rows in L2)
  int bb = swz >> 7;
  int s0 = (swz & 127) * 16;
  int t = threadIdx.x;
  int wave = t >> 6, lane = t & 63;
  int fr = lane & 15, fq = lane >> 4;
  // ---- stage 48 V rows (pad rows from bvb); wave-uniform row per gload16 ----
#pragma unroll
  for (int i = 0; i < 12; ++i) {
    int chunk = t + i * 256;
    int row = chunk >> 6;                // uniform per wave per i
    int c8 = (chunk & 63) * 8;
    int n = s0 + row - WIN;
    const u16* src = (n >= 0 && n < SEQ) ? (Vb + (size_t)(bb * SEQ + n) * EMB + c8)
                                         : (bvb + c8);
    gload16(Vt + (size_t)(wave * 64 + i * 256) * 8, src);
  }
  const float scale = 0.044194173824159216f;  // 1/sqrt(512)
  float ec = *econst_p;
  if (t < 48) {                          // scores for positions s0-16 .. s0+31
    int n = s0 + t - WIN;
    float raw = 0.f;
    if (n >= 0 && n < SEQ) {
      size_t idx = (size_t)bb * SEQ + n;
#pragma unroll
      for (int p = 0; p < 8; ++p) raw += e_part[(size_t)p * MTOT + idx];
    }
    eloc[t] = scale * (raw + ec);        // pad: raw==0 -> scale*bq.bk, exact
  }
  __syncthreads();
  if (t < 16) {
    float ev[WINDOW];
    float mx = -1e30f;
#pragma unroll
    for (int j = 0; j < WINDOW; ++j) { ev[j] = eloc[t + j]; mx = fmaxf(mx, ev[j]); }
    float sum = 0.f;
#pragma unroll
    for (int j = 0; j < WINDOW; ++j) { float ex = __expf(ev[j] - mx); ev[j] = ex; sum += ex; }
    float inv = 1.f / sum;
#pragma unroll
    for (int j = 0; j < WINDOW; ++j) w[t][j] = ev[j] * inv;
  }
  __syncthreads();
  // ---- PV: thread = (col-group cg, row-group slg); 8 cols x 4 rows ----
  int cg = t & 63, slg = t >> 6;
  int d0 = cg * 8;
  float oacc[4][8] = {};
  for (int ri = 0; ri < 36; ++ri) {
    int r = slg * 4 + ri;
    u16x8 v = *reinterpret_cast<const u16x8*>(&Vt[(size_t)r * EMB + d0]);
    float vf[8];
#pragma unroll
    for (int c = 0; c < 8; ++c) vf[c] = bf2f(v[c]);
#pragma unroll
    for (int q = 0; q < 4; ++q) {
      int j = ri - q;
      if (j >= 0 && j < WINDOW) {
        float wt = w[slg * 4 + q][j];
#pragma unroll
        for (int c = 0; c < 8; ++c) oacc[q][c] += wt * vf[c];
      }
    }
  }
  __syncthreads();                       // all PV reads of Vt done
  // ---- write ao tile to LDS: 16 rows x 520 (pad 8) bf16 = 16640 B ----
  u16* aoL = (u16*)smem;
#pragma unroll
  for (int q = 0; q < 4; ++q) {
    u16x8 o;
#pragma unroll
    for (int c = 0; c < 8; ++c) o[c] = f2bf(oacc[q][c]);
    *reinterpret_cast<u16x8*>(aoL + (size_t)(slg * 4 + q) * 520 + d0) = o;
  }
  __syncthreads();
  // ---- O-projection: wave handles 128 cols; out[s][j] = sum_k ao[s][k]*Wo[j][k] + bo[j]
  int n0w = wave * 128;
  f32x4 accO[8] = {};
  for (int kb = 0; kb < EMB; kb += 32) {
    bf16x8 af = *reinterpret_cast<const bf16x8*>(aoL + (size_t)fr * 520 + kb + fq * 8);
#pragma unroll
    for (int nt = 0; nt < 8; ++nt) {
      bf16x8 bf = *reinterpret_cast<const bf16x8*>(
          Wob + (size_t)(n0w + nt * 16 + fr) * EMB + kb + fq * 8);
      accO[nt] = __builtin_amdgcn_mfma_f32_16x16x32_bf16(af, bf, accO[nt], 0, 0, 0);
    }
  }
  size_t rowbase = (size_t)(bb * SEQ + s0 + fq * 4);
#pragma unroll
  for (int nt = 0; nt < 8; ++nt) {
    int col = n0w + nt * 16 + fr;
    float bov = bo[col];
#pragma unroll
    for (int r = 0; r < 4; ++r)
      out[(rowbase + r) * EMB + col] = accO[nt][r] + bov;
  }
}

extern "C" void kernel_launch(void* const* d_in, const int* in_sizes, int n_in,
                              void* d_out, int out_size, void* d_ws, size_t ws_size,
                              hipStream_t stream) {
  const float* x  = (const float*)d_in[0];
  const float* Wq = (const float*)d_in[1];
  const float* bq = (const float*)d_in[2];
  const float* Wk = (const float*)d_in[3];
  const float* bk = (const float*)d_in[4];
  const float* Wv = (const float*)d_in[5];
  const float* bv = (const float*)d_in[6];
  const float* Wo = (const float*)d_in[7];
  const float* bo = (const float*)d_in[8];
  float* out = (float*)d_out;

  char* ws = (char*)d_ws;
  u16* Vb       = (u16*)(ws);                                    // 8 MB
  u16* Atm      = (u16*)(ws + (8u << 20));                       // 512 KB
  u16* Wvb      = (u16*)(ws + (8u << 20) + (512u << 10));        // 512 KB
  u16* Wob      = (u16*)(ws + (8u << 20) + (1024u << 10));       // 512 KB
  float* e_part = (float*)(ws + (8u << 20) + (1536u << 10));     // 256 KB
  float* cvec   = (float*)(ws + (8u << 20) + (1792u << 10));     // 2 KB
  u16* bvb      = (u16*)(ws + (8u << 20) + (1794u << 10));       // 1 KB
  float* econst = (float*)(ws + (8u << 20) + (1795u << 10));     // 4 B

  // 1) weight casts || fp32 atmat || cvec || econst+bvb
  prep1<<<777, 256, 0, stream>>>(Wq, Wk, Wv, Wo, bq, bk, bv,
                                 Wvb, Wob, Atm, bvb, cvec, econst);
  // 2) e partials + V (A self-staged from fp32 x)
  gemm_ev2<<<512, 256, 0, stream>>>(x, Atm, Wvb, bv, cvec, e_part, Vb);
  // 3) window softmax + PV + fused O-projection
  winout<<<512, 256, 0, stream>>>(Vb, e_part, econst, bvb, Wob, bo, out);
}

// Round 6
// 75.420 us; speedup vs baseline: 4.5936x; 1.2208x over previous
//
#include <hip/hip_runtime.h>
#include <stdint.h>

#define SEQ 2048
#define BATCH 4
#define EMB 512
#define MTOT (BATCH * SEQ)   // 8192 rows
#define WIN 16
#define WINDOW 33            // 2*WIN+1

typedef uint32_t u32;
typedef unsigned short u16;
typedef __attribute__((ext_vector_type(8))) __bf16 bf16x8;
typedef __attribute__((ext_vector_type(4))) float f32x4;
typedef __attribute__((ext_vector_type(4))) u16 u16x4;
typedef __attribute__((ext_vector_type(8))) u16 u16x8;

__device__ __forceinline__ u16 f2bf(float f) {  // RNE f32->bf16
  u32 u = __builtin_bit_cast(u32, f);
  u = (u + 0x7fffu + ((u >> 16) & 1u)) >> 16;
  return (u16)u;
}
__device__ __forceinline__ float bf2f(u16 v) {
  return __builtin_bit_cast(float, (u32)v << 16);
}
__device__ __forceinline__ void gload16(void* lds, const void* g) {
  __builtin_amdgcn_global_load_lds((const __attribute__((address_space(1))) u32*)g,
                                   (__attribute__((address_space(3))) u32*)lds, 16, 0, 0);
}
// Explicit drain of LDS-DMA (vm) + ds_write (lgkm) before a publishing barrier.
// The compiler USUALLY emits this before s_barrier; make it unconditional.
__device__ __forceinline__ void drain_stage() {
  asm volatile("s_waitcnt vmcnt(0) lgkmcnt(0)" ::: "memory");
}

// ============ launch 1: Wv/Wo casts || fp32 atmat || cvec || econst+bvb ============
// blocks [0,256): Wv cast | [256,512): Wo cast | [512,768): atmat 32x32 tiles |
// [768,776): cvec | 776: econst + bvb
__global__ void __launch_bounds__(256) prep1(
    const float* __restrict__ Wq, const float* __restrict__ Wk,
    const float* __restrict__ Wv, const float* __restrict__ Wo,
    const float* __restrict__ bq, const float* __restrict__ bk, const float* __restrict__ bv,
    u16* __restrict__ Wvb, u16* __restrict__ Wob, u16* __restrict__ Atm,
    u16* __restrict__ bvb, float* __restrict__ cvec, float* __restrict__ econst) {
  __shared__ float sm[2][32][36];   // atmat tiles (float4-aligned, conflict-free)
  int b = blockIdx.x, t = threadIdx.x;
  if (b < 512) {                          // ---- Wv / Wo cast (float4/thread)
    const float* S = (b < 256) ? Wv : Wo;
    u16* D = (b < 256) ? Wvb : Wob;
    int i = ((b & 255) * 256 + t) * 4;
    float4 v = *reinterpret_cast<const float4*>(S + i);
    u16x4 o; o.x = f2bf(v.x); o.y = f2bf(v.y); o.z = f2bf(v.z); o.w = f2bf(v.w);
    *reinterpret_cast<u16x4*>(D + i) = o;
  } else if (b < 768) {                   // ---- At[n][k] = sum_d Wk[d][n]*Wq[d][k]
    int bid = b - 512;
    int k0 = (bid & 15) * 32, n0 = (bid >> 4) * 32;
    int lr = t >> 5, lc = t & 31;         // lr: 8 row-groups of 4, lc: col
    float acc[4] = {0.f, 0.f, 0.f, 0.f};
    for (int d0 = 0; d0 < EMB; d0 += 32) {
      __syncthreads();
#pragma unroll
      for (int rr = 0; rr < 32; rr += 8) {
        sm[0][rr + lr][lc] = Wk[(size_t)(d0 + rr + lr) * EMB + n0 + lc];
        sm[1][rr + lr][lc] = Wq[(size_t)(d0 + rr + lr) * EMB + k0 + lc];
      }
      __syncthreads();
#pragma unroll 8
      for (int d = 0; d < 32; ++d) {
        float q = sm[1][d][lc];                                   // broadcast per lane
        float4 kv = *reinterpret_cast<const float4*>(&sm[0][d][lr * 4]);  // b128 broadcast
        acc[0] += kv.x * q; acc[1] += kv.y * q; acc[2] += kv.z * q; acc[3] += kv.w * q;
      }
    }
#pragma unroll
    for (int i = 0; i < 4; ++i)
      Atm[(size_t)(n0 + lr * 4 + i) * EMB + k0 + lc] = f2bf(acc[i]);
  } else if (b < 776) {                   // ---- cvec[i] = sum_d Wq[d][i]*bk[d]+Wk[d][i]*bq[d]
    float* sh = &sm[0][0][0];
    int cb = b - 768;
    int ii = t >> 2, di = t & 3;
    int i = cb * 64 + ii;
    float s = 0.f;
    for (int d = di * 128; d < di * 128 + 128; ++d)
      s += Wq[(size_t)d * EMB + i] * bk[d] + Wk[(size_t)d * EMB + i] * bq[d];
    sh[t] = s;
    __syncthreads();
    if (di == 0) cvec[i] = sh[t] + sh[t + 1] + sh[t + 2] + sh[t + 3];
  } else {                                // ---- econst = bq.bk ; bvb cast
    float* sh = &sm[0][0][0];
    bvb[t] = f2bf(bv[t]);
    bvb[t + 256] = f2bf(bv[t + 256]);
    float s = bq[t] * bk[t] + bq[t + 256] * bk[t + 256];
    sh[t] = s;
    __syncthreads();
    for (int st = 128; st > 0; st >>= 1) {
      if (t < st) sh[t] += sh[t + st];
      __syncthreads();
    }
    if (t == 0) *econst = sh[0];
  }
}

// ============ launch 2: E rowdot (by<4) + V GEMM (by>=4); A self-staged from fp32 x ======
__global__ void __launch_bounds__(256) gemm_ev2(
    const float* __restrict__ x, const u16* __restrict__ Atm, const u16* __restrict__ Wvb,
    const float* __restrict__ bv, const float* __restrict__ cvec,
    float* __restrict__ e_part, u16* __restrict__ Vb) {
  __shared__ u16 AtL[128 * 32];
  __shared__ u16 BtL[128 * 32];
  int b = blockIdx.x;                    // 512 blocks
  int wg = ((b & 7) << 6) + (b >> 3);    // XCD-chunked swizzle (bijective: 512 = 8*64)
  int by = wg & 7, bx = wg >> 3;
  bool isE = by < 4;
  int t = threadIdx.x;
  int wave = t >> 6, lane = t & 63;
  int wr = wave >> 1, wc = wave & 1;
  int fr = lane & 15, fq = lane >> 4;
  int m0 = bx * 128;
  int n0 = (by & 3) * 128;
  const u16* Bm = isE ? Atm : Wvb;
  f32x4 acc[4][4] = {};
  for (int kt = 0; kt < EMB / 32; ++kt) {
    __syncthreads();
    int kb = kt * 32;
    // B tile: bf16 source, async DMA to LDS
#pragma unroll
    for (int it = 0; it < 2; ++it) {
      int chunk = t + it * 256;
      int row = chunk >> 2, col = (chunk & 3) * 8;
      gload16(BtL + (size_t)(wave * 64 + it * 256) * 8, Bm + (size_t)(n0 + row) * EMB + kb + col);
    }
    // A tile: fp32 x -> cast -> LDS (reg-staged)
#pragma unroll
    for (int p = 0; p < 4; ++p) {
      int row = p * 32 + (t >> 3), col = (t & 7) * 4;
      float4 v = *reinterpret_cast<const float4*>(x + (size_t)(m0 + row) * EMB + kb + col);
      u16x4 o; o.x = f2bf(v.x); o.y = f2bf(v.y); o.z = f2bf(v.z); o.w = f2bf(v.w);
      *reinterpret_cast<u16x4*>(AtL + row * 32 + col) = o;
    }
    drain_stage();                       // DMA + ds_write fully landed before publish
    __syncthreads();
    bf16x8 af[4], bfv[4];
#pragma unroll
    for (int m = 0; m < 4; ++m)
      af[m] = *reinterpret_cast<const bf16x8*>(&AtL[(wr * 64 + m * 16 + fr) * 32 + fq * 8]);
#pragma unroll
    for (int n = 0; n < 4; ++n)
      bfv[n] = *reinterpret_cast<const bf16x8*>(&BtL[(wc * 64 + n * 16 + fr) * 32 + fq * 8]);
#pragma unroll
    for (int m = 0; m < 4; ++m)
#pragma unroll
      for (int n = 0; n < 4; ++n)
        acc[m][n] = __builtin_amdgcn_mfma_f32_16x16x32_bf16(af[m], bfv[n], acc[m][n], 0, 0, 0);
  }
  if (isE) {
    float cv[4];
#pragma unroll
    for (int n = 0; n < 4; ++n) cv[n] = cvec[n0 + wc * 64 + n * 16 + fr];
#pragma unroll
    for (int m = 0; m < 4; ++m) {
#pragma unroll
      for (int r = 0; r < 4; ++r) {
        int row = m0 + wr * 64 + m * 16 + fq * 4 + r;
        float p = 0.f;
#pragma unroll
        for (int n = 0; n < 4; ++n) {
          int col = n0 + wc * 64 + n * 16 + fr;
          p += (acc[m][n][r] + cv[n]) * x[(size_t)row * EMB + col];
        }
        p += __shfl_xor(p, 1);
        p += __shfl_xor(p, 2);
        p += __shfl_xor(p, 4);
        p += __shfl_xor(p, 8);
        if (fr == 0) e_part[(size_t)(by * 2 + wc) * MTOT + row] = p;
      }
    }
  } else {
    float bvv[4];
#pragma unroll
    for (int n = 0; n < 4; ++n) bvv[n] = bv[n0 + wc * 64 + n * 16 + fr];
#pragma unroll
    for (int m = 0; m < 4; ++m)
#pragma unroll
      for (int n = 0; n < 4; ++n) {
        int col = n0 + wc * 64 + n * 16 + fr;
#pragma unroll
        for (int r = 0; r < 4; ++r) {
          int row = m0 + wr * 64 + m * 16 + fq * 4 + r;
          Vb[(size_t)row * EMB + col] = f2bf(acc[m][n][r] + bvv[n]);
        }
      }
  }
}

// ============ launch 3: window softmax + weighted V sum -> ao (bf16) ============
// V staged via plain loads + ds_write_b128 (no LDS-DMA: divergent pad source).
__global__ void __launch_bounds__(256) window2(
    const u16* __restrict__ Vb, const float* __restrict__ e_part,
    const float* __restrict__ econst_p, const u16* __restrict__ bvb,
    u16* __restrict__ ao) {
  __shared__ u16 Vt[48 * EMB];      // 48 rows x 512 bf16 = 49152 B
  __shared__ float eloc[48];
  __shared__ float w[16][WINDOW];
  int b = blockIdx.x;                    // 512 blocks
  int swz = ((b & 7) << 6) + (b >> 3);   // XCD-chunked: neighbor s0 share V halo in L2
  int bb = swz >> 7;
  int s0 = (swz & 127) * 16;
  int t = threadIdx.x;
  // ---- stage 48 V rows: issue all 12 loads, then 12 ds_writes (reg-staged) ----
  u16x8 stg[12];
#pragma unroll
  for (int i = 0; i < 12; ++i) {
    int chunk = t + i * 256;
    int row = chunk >> 6;
    int c8 = (chunk & 63) * 8;
    int n = s0 + row - WIN;
    const u16* src = (n >= 0 && n < SEQ) ? (Vb + (size_t)(bb * SEQ + n) * EMB + c8)
                                         : (bvb + c8);
    stg[i] = *reinterpret_cast<const u16x8*>(src);
  }
#pragma unroll
  for (int i = 0; i < 12; ++i) {
    int chunk = t + i * 256;
    int row = chunk >> 6;
    int c8 = (chunk & 63) * 8;
    *reinterpret_cast<u16x8*>(&Vt[(size_t)row * EMB + c8]) = stg[i];
  }
  const float scale = 0.044194173824159216f;  // 1/sqrt(512)
  float ec = *econst_p;
  if (t < 48) {                          // scores for positions s0-16 .. s0+31
    int n = s0 + t - WIN;
    float raw = 0.f;
    if (n >= 0 && n < SEQ) {
      size_t idx = (size_t)bb * SEQ + n;
#pragma unroll
      for (int p = 0; p < 8; ++p) raw += e_part[(size_t)p * MTOT + idx];
    }
    eloc[t] = scale * (raw + ec);        // pad: raw==0 -> scale*bq.bk, exact
  }
  __syncthreads();
  if (t < 16) {
    float ev[WINDOW];
    float mx = -1e30f;
#pragma unroll
    for (int j = 0; j < WINDOW; ++j) { ev[j] = eloc[t + j]; mx = fmaxf(mx, ev[j]); }
    float sum = 0.f;
#pragma unroll
    for (int j = 0; j < WINDOW; ++j) { float ex = __expf(ev[j] - mx); ev[j] = ex; sum += ex; }
    float inv = 1.f / sum;
#pragma unroll
    for (int j = 0; j < WINDOW; ++j) w[t][j] = ev[j] * inv;
  }
  __syncthreads();
  // each thread: 8 columns x 4 query rows; read each V row once (b128)
  int cg = t & 63;
  int slg = t >> 6;                      // query group of 4
  int d0 = cg * 8;
  float oacc[4][8] = {};
  for (int ri = 0; ri < 36; ++ri) {
    int r = slg * 4 + ri;
    u16x8 v = *reinterpret_cast<const u16x8*>(&Vt[(size_t)r * EMB + d0]);
    float vf[8];
#pragma unroll
    for (int c = 0; c < 8; ++c) vf[c] = bf2f(v[c]);
#pragma unroll
    for (int q = 0; q < 4; ++q) {
      int j = ri - q;                    // compile-time per (ri,q)
      if (j >= 0 && j < WINDOW) {
        float wt = w[slg * 4 + q][j];
#pragma unroll
        for (int c = 0; c < 8; ++c) oacc[q][c] += wt * vf[c];
      }
    }
  }
#pragma unroll
  for (int q = 0; q < 4; ++q) {
    u16x8 o;
#pragma unroll
    for (int c = 0; c < 8; ++c) o[c] = f2bf(oacc[q][c]);
    *reinterpret_cast<u16x8*>(&ao[(size_t)(bb * SEQ + s0 + slg * 4 + q) * EMB + d0]) = o;
  }
}

// ============ launch 4: out = ao @ Wo^T + bo (fp32), 64x128 tiles, 512 blocks ============
__global__ void __launch_bounds__(256) ogemm(
    const u16* __restrict__ ao, const u16* __restrict__ Wob,
    const float* __restrict__ bo, float* __restrict__ out) {
  __shared__ u16 At2[64 * 32];    // 4 KB
  __shared__ u16 Bt2[128 * 32];   // 8 KB
  int b = blockIdx.x;                    // 512 blocks
  int wg = ((b & 7) << 6) + (b >> 3);    // XCD-chunked swizzle
  int bx = wg >> 2, by = wg & 3;
  int t = threadIdx.x;
  int wave = t >> 6, lane = t & 63;
  int wr = wave >> 1, wc = wave & 1;
  int fr = lane & 15, fq = lane >> 4;
  int m0 = bx * 64, n0 = by * 128;
  f32x4 acc[2][4] = {};
  for (int kt = 0; kt < EMB / 32; ++kt) {
    __syncthreads();
    int kb = kt * 32;
    {
      int row = t >> 2, col = (t & 3) * 8;
      gload16(At2 + (size_t)t * 8, ao + (size_t)(m0 + row) * EMB + kb + col);
    }
#pragma unroll
    for (int it = 0; it < 2; ++it) {
      int chunk = t + it * 256;
      int row = chunk >> 2, col = (chunk & 3) * 8;
      gload16(Bt2 + (size_t)(wave * 64 + it * 256) * 8, Wob + (size_t)(n0 + row) * EMB + kb + col);
    }
    drain_stage();                       // DMA fully landed before publish
    __syncthreads();
    bf16x8 af[2], bfv[4];
#pragma unroll
    for (int m = 0; m < 2; ++m)
      af[m] = *reinterpret_cast<const bf16x8*>(&At2[(wr * 32 + m * 16 + fr) * 32 + fq * 8]);
#pragma unroll
    for (int n = 0; n < 4; ++n)
      bfv[n] = *reinterpret_cast<const bf16x8*>(&Bt2[(wc * 64 + n * 16 + fr) * 32 + fq * 8]);
#pragma unroll
    for (int m = 0; m < 2; ++m)
#pragma unroll
      for (int n = 0; n < 4; ++n)
        acc[m][n] = __builtin_amdgcn_mfma_f32_16x16x32_bf16(af[m], bfv[n], acc[m][n], 0, 0, 0);
  }
  float bov[4];
#pragma unroll
  for (int n = 0; n < 4; ++n) bov[n] = bo[n0 + wc * 64 + n * 16 + fr];
#pragma unroll
  for (int m = 0; m < 2; ++m)
#pragma unroll
    for (int n = 0; n < 4; ++n) {
      int col = n0 + wc * 64 + n * 16 + fr;
#pragma unroll
      for (int r = 0; r < 4; ++r) {
        int row = m0 + wr * 32 + m * 16 + fq * 4 + r;
        out[(size_t)row * EMB + col] = acc[m][n][r] + bov[n];
      }
    }
}

extern "C" void kernel_launch(void* const* d_in, const int* in_sizes, int n_in,
                              void* d_out, int out_size, void* d_ws, size_t ws_size,
                              hipStream_t stream) {
  const float* x  = (const float*)d_in[0];
  const float* Wq = (const float*)d_in[1];
  const float* bq = (const float*)d_in[2];
  const float* Wk = (const float*)d_in[3];
  const float* bk = (const float*)d_in[4];
  const float* Wv = (const float*)d_in[5];
  const float* bv = (const float*)d_in[6];
  const float* Wo = (const float*)d_in[7];
  const float* bo = (const float*)d_in[8];
  float* out = (float*)d_out;

  char* ws = (char*)d_ws;
  u16* Vb       = (u16*)(ws);                                    // 8 MB
  u16* ao       = (u16*)(ws + (8u << 20));                       // 8 MB
  u16* Atm      = (u16*)(ws + (16u << 20));                      // 512 KB
  u16* Wvb      = (u16*)(ws + (16u << 20) + (512u << 10));       // 512 KB
  u16* Wob      = (u16*)(ws + (16u << 20) + (1024u << 10));      // 512 KB
  float* e_part = (float*)(ws + (16u << 20) + (1536u << 10));    // 256 KB
  float* cvec   = (float*)(ws + (16u << 20) + (1792u << 10));    // 2 KB
  u16* bvb      = (u16*)(ws + (16u << 20) + (1794u << 10));      // 1 KB
  float* econst = (float*)(ws + (16u << 20) + (1795u << 10));    // 4 B

  // 1) weight casts || fp32 atmat || cvec || econst+bvb
  prep1<<<777, 256, 0, stream>>>(Wq, Wk, Wv, Wo, bq, bk, bv,
                                 Wvb, Wob, Atm, bvb, cvec, econst);
  // 2) e partials + V (A self-staged from fp32 x)
  gemm_ev2<<<512, 256, 0, stream>>>(x, Atm, Wvb, bv, cvec, e_part, Vb);
  // 3) window softmax + PV -> ao (bf16)
  window2<<<512, 256, 0, stream>>>(Vb, e_part, econst, bvb, ao);
  // 4) out = ao @ Wo^T + bo
  ogemm<<<512, 256, 0, stream>>>(ao, Wob, bo, out);
}